// Round 3
// baseline (267.077 us; speedup 1.0000x reference)
//
#include <hip/hip_runtime.h>
#include <math.h>

typedef __bf16 bf16_t;
typedef __bf16 bf16x8 __attribute__((ext_vector_type(8)));
typedef __bf16 bf16x4 __attribute__((ext_vector_type(4)));
typedef float f32x4 __attribute__((ext_vector_type(4)));

#define MFMA16(a, b, c) __builtin_amdgcn_mfma_f32_16x16x32_bf16((a), (b), (c), 0, 0, 0)

constexpr int Bc = 2, Nc = 2048, Dc = 1024, Hc = 16, HDc = 64;
constexpr float C1 = 0.18033688011112042f;     // 0.125 * log2(e), folded into Q at qkv epilogue
constexpr float LOG2E = 1.4426950408889634f;

// async global->LDS, 16B per lane; LDS base must be wave-uniform (HW adds lane*16)
__device__ __forceinline__ void glds16(const bf16_t* g, bf16_t* l) {
    __builtin_amdgcn_global_load_lds(
        (const __attribute__((address_space(1))) unsigned int*)g,
        (__attribute__((address_space(3))) unsigned int*)l, 16, 0, 0);
}

// async global->LDS, 4B per lane (HW adds lane*4)
__device__ __forceinline__ void glds4(const float* g, float* l) {
    __builtin_amdgcn_global_load_lds(
        (const __attribute__((address_space(1))) unsigned int*)g,
        (__attribute__((address_space(3))) unsigned int*)l, 4, 0, 0);
}

// ---------------------------------------------------------------------------
__device__ __forceinline__ void tr64_body(const float* __restrict__ src,
                                          bf16_t* __restrict__ dst, int R, int C,
                                          int bx, int by, bf16_t* tile, int t) {
    int r0 = by * 64, c0 = bx * 64;
    int cl = t & 63, rl = t >> 6;
#pragma unroll
    for (int p = 0; p < 16; ++p) {
        int r = p * 4 + rl;
        tile[r * 66 + cl] = (bf16_t)src[(size_t)(r0 + r) * C + c0 + cl];
    }
    __syncthreads();
#pragma unroll
    for (int p = 0; p < 16; ++p) {
        int r = p * 4 + rl;
        dst[(size_t)(c0 + r) * R + r0 + cl] = tile[cl * 66 + r];
    }
}

// ---------------------------------------------------------------------------
// Fused prep: f2b (4096 blk) | tr64 w_qkv (768) | tr64 w_out (256) |
//             pool_partial (256) | covbias-no-g (256). All independent jobs;
// one dispatch instead of five, and the memory-bound pieces overlap.
__global__ __launch_bounds__(256) void prep(const float* __restrict__ x,
                                            bf16_t* __restrict__ Xb,
                                            const float* __restrict__ w_qkv,
                                            bf16_t* __restrict__ Wt,
                                            const float* __restrict__ w_out,
                                            bf16_t* __restrict__ WoT,
                                            float* __restrict__ pooled,
                                            const float* __restrict__ coverage,
                                            const float* __restrict__ w_ce1,
                                            const float* __restrict__ b_ce1,
                                            const float* __restrict__ w_ce2,
                                            const float* __restrict__ b_ce2,
                                            float* __restrict__ cbias) {
    __shared__ bf16_t tile[64 * 66];
    int bid = blockIdx.x, t = threadIdx.x;
    if (bid < 4096) {                       // f2b: x -> bf16
        int i = (bid * 256 + t) * 4;
        float4 v = *(const float4*)(x + i);
        bf16x4 o = { (bf16_t)v.x, (bf16_t)v.y, (bf16_t)v.z, (bf16_t)v.w };
        *(bf16x4*)(Xb + i) = o;
    } else if (bid < 4864) {                // transpose w_qkv
        int bb = bid - 4096;
        tr64_body(w_qkv, Wt, 1024, 3072, bb % 48, bb / 48, tile, t);
    } else if (bid < 5120) {                // transpose w_out
        int bb = bid - 4864;
        tr64_body(w_out, WoT, 1024, 1024, bb & 15, bb >> 4, tile, t);
    } else if (bid < 5376) {                // pool partial sums
        int blk = bid - 5120;
        int b = blk >> 7, ch = blk & 127;
        int c = t * 4;
        float s0 = 0.f, s1 = 0.f, s2 = 0.f, s3 = 0.f;
        for (int rr = 0; rr < 16; ++rr) {
            float4 v = *(const float4*)(x + (size_t)(b * Nc + ch * 16 + rr) * Dc + c);
            s0 += v.x; s1 += v.y; s2 += v.z; s3 += v.w;
        }
        atomicAdd(&pooled[b * Dc + c + 0], s0);
        atomicAdd(&pooled[b * Dc + c + 1], s1);
        atomicAdd(&pooled[b * Dc + c + 2], s2);
        atomicAdd(&pooled[b * Dc + c + 3], s3);
    } else {                                // coverage-bias WITHOUT gate g
        int blk = bid - 5376;
        int h = t & 15;
        int gn = blk * 16 + (t >> 4);
        int b = gn >> 11, n = gn & 2047;
        float c = coverage[gn];
        float acc = b_ce2[h];
        for (int j = 0; j < 256; ++j) {
            float tv = c * w_ce1[j] + b_ce1[j];
            tv = tv / (1.0f + __expf(-tv));
            acc += tv * w_ce2[j * 16 + h];
        }
        cbias[((size_t)b * 16 + h) * 2048 + n] = LOG2E * acc;
    }
}

// ---------------------------------------------------------------------------
// QKV GEMM (y<24) + gate MLP (y==24, 32 blocks, 16 (b,j) pairs each).
// Q pre-scaled by C1 = 0.125*log2(e) so attn can use exp2 with no FMA.
__global__ __launch_bounds__(256) void qkv_gemm(const bf16_t* __restrict__ Xb,
                                                const bf16_t* __restrict__ Wt,
                                                bf16_t* __restrict__ Q,
                                                bf16_t* __restrict__ Kb,
                                                bf16_t* __restrict__ Vt,
                                                const float* __restrict__ pooled,
                                                const float* __restrict__ w_fg1,
                                                const float* __restrict__ b_fg1,
                                                const float* __restrict__ w_fg2,
                                                float* __restrict__ hacc) {
    __shared__ __align__(16) bf16_t At[128 * 32];
    __shared__ __align__(16) bf16_t Bt[128 * 32];
    int t = threadIdx.x;

    if (blockIdx.y == 24) {                 // gate MLP: hacc[b] += silu(h_j)*w_fg2[j]
        __shared__ float red[4];
        int blk = blockIdx.x;
        int b = blk >> 4, jb = (blk & 15) * 16;
        for (int jj = 0; jj < 16; ++jj) {
            int j = jb + jj;
            float p = 0.f;
#pragma unroll
            for (int i = 0; i < 4; ++i) {
                int d = t * 4 + i;
                p += pooled[b * 1024 + d] * w_fg1[d * 256 + j];
            }
#pragma unroll
            for (int off = 32; off > 0; off >>= 1) p += __shfl_down(p, off);
            if ((t & 63) == 0) red[t >> 6] = p;
            __syncthreads();
            if (t == 0) {
                float hj = (red[0] + red[1] + red[2] + red[3]) * (1.0f / 2048.0f) + b_fg1[j];
                hj = hj / (1.0f + __expf(-hj)); // silu
                atomicAdd(&hacc[b], hj * w_fg2[j]);
            }
            __syncthreads();
        }
        return;
    }

    int w = t >> 6, lane = t & 63;
    int l16 = lane & 15, quad = lane >> 4;
    int wm = w & 1, wx = w >> 1;
    int m0 = blockIdx.x * 128;
    int n0 = blockIdx.y * 128;
    f32x4 acc[4][4] = {};
    int sw = (l16 >> 2) & 3;

    for (int k0 = 0; k0 < 1024; k0 += 32) {
#pragma unroll
        for (int i = 0; i < 2; ++i) {
            int fb = i * 4096 + w * 1024;
            int f = fb + lane * 16;
            int row = f >> 6;
            int ch = (f >> 4) & 3;
            int sc = ch ^ ((row >> 2) & 3);
            glds16(Wt + (size_t)(n0 + row) * 1024 + k0 + sc * 8, At + (fb >> 1));
            glds16(Xb + (size_t)(m0 + row) * 1024 + k0 + sc * 8, Bt + (fb >> 1));
        }
        __syncthreads();
        bf16x8 afr[4], bfr[4];
#pragma unroll
        for (int mi = 0; mi < 4; ++mi)
            afr[mi] = *(const bf16x8*)(At + (wm * 64 + mi * 16 + l16) * 32 + ((quad ^ sw) * 8));
#pragma unroll
        for (int ni = 0; ni < 4; ++ni)
            bfr[ni] = *(const bf16x8*)(Bt + (wx * 64 + ni * 16 + l16) * 32 + ((quad ^ sw) * 8));
#pragma unroll
        for (int mi = 0; mi < 4; ++mi)
#pragma unroll
            for (int ni = 0; ni < 4; ++ni)
                acc[mi][ni] = MFMA16(afr[mi], bfr[ni], acc[mi][ni]);
        __syncthreads();
    }

    int sec = n0 >> 10;
    float scq = (sec == 0) ? C1 : 1.0f;
#pragma unroll
    for (int mi = 0; mi < 4; ++mi) {
        int gc = n0 + wm * 64 + mi * 16 + quad * 4;
        int dcol = gc & 1023;
        int h = dcol >> 6, hd = dcol & 63;
#pragma unroll
        for (int ni = 0; ni < 4; ++ni) {
            int gx = m0 + wx * 64 + ni * 16 + l16;
            int b = gx >> 11, n = gx & 2047;
            size_t bh = (size_t)(b * 16 + h);
            if (sec == 2) {
#pragma unroll
                for (int r = 0; r < 4; ++r)
                    Vt[(bh * 64 + hd + r) * 2048 + n] = (bf16_t)acc[mi][ni][r];
            } else {
                bf16x4 pk = { (bf16_t)(acc[mi][ni][0] * scq), (bf16_t)(acc[mi][ni][1] * scq),
                              (bf16_t)(acc[mi][ni][2] * scq), (bf16_t)(acc[mi][ni][3] * scq) };
                bf16_t* dst = (sec == 0 ? Q : Kb);
                *(bf16x4*)(dst + (bh * 2048 + n) * 64 + hd) = pk;
            }
        }
    }
}

// ---------------------------------------------------------------------------
// Flash attention v6: 2 waves x 32 q = 64 q/block, grid (32,32) = 1024 blocks
// (4 independent blocks/CU, finer barrier groups). Counted-vmcnt pipeline,
// hoisted per-thread LDS offsets (base + compile-time immediate inside loop).
// Gate g applied to the staged bias (covbias no longer depends on the gate).
__global__ __launch_bounds__(128) void attn_k(const bf16_t* __restrict__ Q,
                                              const bf16_t* __restrict__ Kb,
                                              const bf16_t* __restrict__ Vt,
                                              const float* __restrict__ cbias,
                                              const float* __restrict__ hacc,
                                              const float* __restrict__ b_fg2,
                                              bf16_t* __restrict__ O) {
    __shared__ __align__(16) bf16_t kbuf[2][64 * 64];
    __shared__ __align__(16) bf16_t vbuf[2][64 * 64];
    __shared__ __align__(16) float bbias[2][64];
    int t = threadIdx.x, w = t >> 6, lane = t & 63;
    int l16 = lane & 15, quad = lane >> 4;
    int bh = blockIdx.y;
    int b = bh >> 4, h = bh & 15;
    int qa = blockIdx.x * 64 + w * 32;
    const bf16_t* Qh = Q + (size_t)bh * 2048 * 64;
    const bf16_t* Kh = Kb + (size_t)bh * 2048 * 64;
    const bf16_t* Vh = Vt + (size_t)bh * 64 * 2048;
    const float* bih = cbias + (size_t)bh * 2048;
    float g = 1.0f / (1.0f + __expf(-(hacc[b] + b_fg2[0])));

    // per-wave staging decomposition: wave w covers bytes [w*4096, w*4096+4096)
    int krow[4], ksc[4];
#pragma unroll
    for (int c = 0; c < 4; ++c) {
        int f = w * 4096 + c * 1024 + lane * 16;
        int row = f >> 7, ch = (f >> 4) & 7;
        krow[c] = row;
        ksc[c] = ch ^ (row & 7);
    }

    bf16x8 qf[2][2];
#pragma unroll
    for (int qt = 0; qt < 2; ++qt)
#pragma unroll
        for (int dh = 0; dh < 2; ++dh)
            qf[qt][dh] = *(const bf16x8*)(Qh + (size_t)(qa + qt * 16 + l16) * 64 + dh * 32 + quad * 8);

    f32x4 o[2][4] = {};
    f32x4 lacc[2] = {};
    bf16x8 onesb;
#pragma unroll
    for (int i = 0; i < 8; ++i) onesb[i] = (bf16_t)1.0f;
    int swl = l16 & 7;
    int qh = quad >> 1, ql = quad & 1;

    // per-thread invariant LDS read offsets (elements); loop adds imm only
    int bk0 = l16 * 64 + ((quad ^ swl) * 8);
    int bk1 = l16 * 64 + (((4 + quad) ^ swl) * 8);
    int bv0 = l16 * 64 + ql * 4 + ((qh ^ swl) * 8);
    int bv1 = l16 * 64 + ql * 4 + (((2 + qh) ^ swl) * 8);
    int bv2 = l16 * 64 + ql * 4 + (((4 + qh) ^ swl) * 8);
    int bv3 = l16 * 64 + ql * 4 + (((6 + qh) ^ swl) * 8);

    // stage tile into buffer bf: 9 vmem ops per wave (K4 + V4 + bias1)
    auto stage = [&](int tile_, int bf) {
        int jn = tile_ * 64;
        bf16_t* kd = &kbuf[bf][w * 2048];
        bf16_t* vd = &vbuf[bf][w * 2048];
#pragma unroll
        for (int c = 0; c < 4; ++c)
            glds16(Kh + (size_t)(jn + krow[c]) * 64 + ksc[c] * 8, kd + c * 512);
#pragma unroll
        for (int c = 0; c < 4; ++c)
            glds16(Vh + (size_t)krow[c] * 2048 + jn + ksc[c] * 8, vd + c * 512);
        glds4(bih + jn + lane, &bbias[bf][0]);   // both waves write same values (benign)
    };

    stage(0, 0);

    for (int it = 0; it < 32; ++it) {
        int sel = it & 1;
        asm volatile("s_waitcnt lgkmcnt(0)" ::: "memory");
        __builtin_amdgcn_s_barrier();            // everyone done reading buf[sel^1]
        if (it + 1 < 32) {
            stage(it + 1, sel ^ 1);              // outstanding: 18
            asm volatile("s_waitcnt vmcnt(9)" ::: "memory");   // tile-it loads done
        } else {
            asm volatile("s_waitcnt vmcnt(0)" ::: "memory");
        }
        __builtin_amdgcn_s_barrier();            // tile-it data visible to both waves
        __builtin_amdgcn_sched_barrier(0);

        const bf16_t* kb = &kbuf[sel][0];
        const bf16_t* vb = &vbuf[sel][0];
        const float* bp = &bbias[sel][0];

        f32x4 s[2][4];
        __builtin_amdgcn_s_setprio(1);
#pragma unroll
        for (int kt = 0; kt < 4; ++kt) {
            f32x4 bv = *(const f32x4*)(bp + kt * 16 + quad * 4);   // LDS broadcast
            f32x4 bi = { bv[0] * g, bv[1] * g, bv[2] * g, bv[3] * g };
            bf16x8 kf0 = *(const bf16x8*)(kb + kt * 1024 + bk0);
            bf16x8 kf1 = *(const bf16x8*)(kb + kt * 1024 + bk1);
#pragma unroll
            for (int qt = 0; qt < 2; ++qt) {
                s[qt][kt] = MFMA16(kf0, qf[qt][0], bi);
                s[qt][kt] = MFMA16(kf1, qf[qt][1], s[qt][kt]);
            }
        }
        __builtin_amdgcn_s_setprio(0);

        bf16x8 pf[2][2];
#pragma unroll
        for (int qt = 0; qt < 2; ++qt) {
#pragma unroll
            for (int kt = 0; kt < 4; ++kt)
#pragma unroll
                for (int r = 0; r < 4; ++r)
                    s[qt][kt][r] = __builtin_amdgcn_exp2f(s[qt][kt][r]);
#pragma unroll
            for (int pv = 0; pv < 2; ++pv) {
                bf16x8 tmp;
#pragma unroll
                for (int i = 0; i < 4; ++i) {
                    tmp[i]     = (bf16_t)s[qt][2 * pv][i];
                    tmp[i + 4] = (bf16_t)s[qt][2 * pv + 1][i];
                }
                pf[qt][pv] = tmp;
            }
        }

        __builtin_amdgcn_s_setprio(1);
#pragma unroll
        for (int qt = 0; qt < 2; ++qt) {
            lacc[qt] = MFMA16(pf[qt][0], onesb, lacc[qt]);
            lacc[qt] = MFMA16(pf[qt][1], onesb, lacc[qt]);
        }
#pragma unroll
        for (int dt = 0; dt < 4; ++dt) {
            bf16x4 va0 = *(const bf16x4*)(vb + dt * 1024 + bv0);
            bf16x4 vc0 = *(const bf16x4*)(vb + dt * 1024 + bv1);
            bf16x8 vf0 = __builtin_shufflevector(va0, vc0, 0, 1, 2, 3, 4, 5, 6, 7);
            bf16x4 va1 = *(const bf16x4*)(vb + dt * 1024 + bv2);
            bf16x4 vc1 = *(const bf16x4*)(vb + dt * 1024 + bv3);
            bf16x8 vf1 = __builtin_shufflevector(va1, vc1, 0, 1, 2, 3, 4, 5, 6, 7);
#pragma unroll
            for (int qt = 0; qt < 2; ++qt) {
                o[qt][dt] = MFMA16(pf[qt][0], vf0, o[qt][dt]);
                o[qt][dt] = MFMA16(pf[qt][1], vf1, o[qt][dt]);
            }
        }
        __builtin_amdgcn_s_setprio(0);
    }

#pragma unroll
    for (int qt = 0; qt < 2; ++qt) {
        f32x4 rinv;
#pragma unroll
        for (int r = 0; r < 4; ++r) rinv[r] = 1.0f / lacc[qt][r];
#pragma unroll
        for (int dt = 0; dt < 4; ++dt)
#pragma unroll
            for (int r = 0; r < 4; ++r) {
                int row = qa + qt * 16 + quad * 4 + r;
                O[(size_t)(b * 2048 + row) * 1024 + h * 64 + dt * 16 + l16] =
                    (bf16_t)(o[qt][dt][r] * rinv[r]);
            }
    }
}

// ---------------------------------------------------------------------------
__global__ __launch_bounds__(256) void out_gemm(const bf16_t* __restrict__ A,
                                                const bf16_t* __restrict__ Wt,
                                                const float* __restrict__ bias,
                                                float* __restrict__ Cout) {
    __shared__ __align__(16) bf16_t At[128 * 32];
    __shared__ __align__(16) bf16_t Bt[128 * 32];
    int t = threadIdx.x, w = t >> 6, lane = t & 63;
    int l16 = lane & 15, quad = lane >> 4;
    int wm = w & 1, wx = w >> 1;
    int m0 = blockIdx.x * 128;
    int n0 = blockIdx.y * 128;
    f32x4 acc[4][4] = {};
    int sw = (l16 >> 2) & 3;

    for (int k0 = 0; k0 < 1024; k0 += 32) {
#pragma unroll
        for (int i = 0; i < 2; ++i) {
            int fb = i * 4096 + w * 1024;
            int f = fb + lane * 16;
            int row = f >> 6;
            int ch = (f >> 4) & 3;
            int sc = ch ^ ((row >> 2) & 3);
            glds16(Wt + (size_t)(n0 + row) * 1024 + k0 + sc * 8, At + (fb >> 1));
            glds16(A + (size_t)(m0 + row) * 1024 + k0 + sc * 8, Bt + (fb >> 1));
        }
        __syncthreads();
        bf16x8 afr[4], bfr[4];
#pragma unroll
        for (int mi = 0; mi < 4; ++mi)
            afr[mi] = *(const bf16x8*)(At + (wm * 64 + mi * 16 + l16) * 32 + ((quad ^ sw) * 8));
#pragma unroll
        for (int ni = 0; ni < 4; ++ni)
            bfr[ni] = *(const bf16x8*)(Bt + (wx * 64 + ni * 16 + l16) * 32 + ((quad ^ sw) * 8));
#pragma unroll
        for (int mi = 0; mi < 4; ++mi)
#pragma unroll
            for (int ni = 0; ni < 4; ++ni)
                acc[mi][ni] = MFMA16(afr[mi], bfr[ni], acc[mi][ni]);
        __syncthreads();
    }

#pragma unroll
    for (int mi = 0; mi < 4; ++mi) {
        int gc = n0 + wm * 64 + mi * 16 + quad * 4;
        float4 bv = *(const float4*)(bias + gc);
#pragma unroll
        for (int ni = 0; ni < 4; ++ni) {
            int gx = m0 + wx * 64 + ni * 16 + l16;
            float4 ov = { acc[mi][ni][0] + bv.x, acc[mi][ni][1] + bv.y,
                          acc[mi][ni][2] + bv.z, acc[mi][ni][3] + bv.w };
            *(float4*)(Cout + (size_t)gx * 1024 + gc) = ov;
        }
    }
}

// ---------------------------------------------------------------------------
extern "C" void kernel_launch(void* const* d_in, const int* in_sizes, int n_in,
                              void* d_out, int out_size, void* d_ws, size_t ws_size,
                              hipStream_t stream) {
    const float* x     = (const float*)d_in[0];
    const float* cov   = (const float*)d_in[1];
    const float* w_qkv = (const float*)d_in[2];
    const float* w_out = (const float*)d_in[3];
    const float* b_out = (const float*)d_in[4];
    const float* w_ce1 = (const float*)d_in[5];
    const float* b_ce1 = (const float*)d_in[6];
    const float* w_ce2 = (const float*)d_in[7];
    const float* b_ce2 = (const float*)d_in[8];
    const float* w_fg1 = (const float*)d_in[9];
    const float* b_fg1 = (const float*)d_in[10];
    const float* w_fg2 = (const float*)d_in[11];
    const float* b_fg2 = (const float*)d_in[12];

    char* ws = (char*)d_ws;
    bf16_t* Wt     = (bf16_t*)(ws);              // 3072x1024
    bf16_t* WoT    = (bf16_t*)(ws + 6291456);    // 1024x1024
    bf16_t* Xb     = (bf16_t*)(ws + 8388608);    // 4096x1024
    bf16_t* Qb     = (bf16_t*)(ws + 16777216);   // (2,16,2048,64)
    bf16_t* Kbb    = (bf16_t*)(ws + 25165824);   // (2,16,2048,64)
    bf16_t* Vt     = (bf16_t*)(ws + 33554432);   // (2,16,64,2048)
    bf16_t* Ob     = (bf16_t*)(ws + 41943040);   // (4096,1024)
    float*  pooled = (float*)(ws + 50331648);    // 2x1024 f32
    float*  hacc   = (float*)(ws + 50339840);    // 2 f32 (contiguous after pooled)
    float*  biasb  = (float*)(ws + 50340096);    // 2x16x2048 f32 (no g applied)

    // pooled (8192 B) and hacc (8 B) are contiguous: one memset
    hipMemsetAsync(pooled, 0, 8200, stream);
    prep<<<5632, 256, 0, stream>>>(x, Xb, w_qkv, Wt, w_out, WoT, pooled,
                                   cov, w_ce1, b_ce1, w_ce2, b_ce2, biasb);
    qkv_gemm<<<dim3(32, 25), 256, 0, stream>>>(Xb, Wt, Qb, Kbb, Vt,
                                               pooled, w_fg1, b_fg1, w_fg2, hacc);
    attn_k<<<dim3(32, 32), 128, 0, stream>>>(Qb, Kbb, Vt, biasb, hacc, b_fg2, Ob);
    out_gemm<<<dim3(32, 8), 256, 0, stream>>>(Ob, WoT, b_out, (float*)d_out);
}

// Round 5
// 240.258 us; speedup vs baseline: 1.1116x; 1.1116x over previous
//
#include <hip/hip_runtime.h>
#include <math.h>

typedef __bf16 bf16_t;
typedef __bf16 bf16x8 __attribute__((ext_vector_type(8)));
typedef __bf16 bf16x4 __attribute__((ext_vector_type(4)));
typedef float f32x4 __attribute__((ext_vector_type(4)));

#define MFMA16(a, b, c) __builtin_amdgcn_mfma_f32_16x16x32_bf16((a), (b), (c), 0, 0, 0)

constexpr int Bc = 2, Nc = 2048, Dc = 1024, Hc = 16, HDc = 64;
constexpr float C1 = 0.18033688011112042f;     // 0.125 * log2(e), folded into Q at qkv epilogue
constexpr float LOG2E = 1.4426950408889634f;

// async global->LDS, 16B per lane; LDS base must be wave-uniform (HW adds lane*16)
__device__ __forceinline__ void glds16(const bf16_t* g, bf16_t* l) {
    __builtin_amdgcn_global_load_lds(
        (const __attribute__((address_space(1))) unsigned int*)g,
        (__attribute__((address_space(3))) unsigned int*)l, 16, 0, 0);
}

// async global->LDS, 4B per lane (HW adds lane*4)
__device__ __forceinline__ void glds4(const float* g, float* l) {
    __builtin_amdgcn_global_load_lds(
        (const __attribute__((address_space(1))) unsigned int*)g,
        (__attribute__((address_space(3))) unsigned int*)l, 4, 0, 0);
}

// ---------------------------------------------------------------------------
__device__ __forceinline__ void tr64_body(const float* __restrict__ src,
                                          bf16_t* __restrict__ dst, int R, int C,
                                          int bx, int by, bf16_t* tile, int t) {
    int r0 = by * 64, c0 = bx * 64;
    int cl = t & 63, rl = t >> 6;
#pragma unroll
    for (int p = 0; p < 16; ++p) {
        int r = p * 4 + rl;
        tile[r * 66 + cl] = (bf16_t)src[(size_t)(r0 + r) * C + c0 + cl];
    }
    __syncthreads();
#pragma unroll
    for (int p = 0; p < 16; ++p) {
        int r = p * 4 + rl;
        dst[(size_t)(c0 + r) * R + r0 + cl] = tile[cl * 66 + r];
    }
}

// ---------------------------------------------------------------------------
// Fused prep. Long-pole jobs get the LOWEST block ids so they start first.
//   bid [0,64)      covbias (LDS-resident two-phase, no g)
//   bid [64,320)    pool partial sums
//   bid [320,1088)  transpose w_qkv
//   bid [1088,1344) transpose w_out
//   bid [1344,2368) f2b: 4096 floats/block (256 thr x 4 chunks x float4)
__global__ __launch_bounds__(256) void prep(const float* __restrict__ x,
                                            bf16_t* __restrict__ Xb,
                                            const float* __restrict__ w_qkv,
                                            bf16_t* __restrict__ Wt,
                                            const float* __restrict__ w_out,
                                            bf16_t* __restrict__ WoT,
                                            float* __restrict__ pooled,
                                            const float* __restrict__ coverage,
                                            const float* __restrict__ w_ce1,
                                            const float* __restrict__ b_ce1,
                                            const float* __restrict__ w_ce2,
                                            const float* __restrict__ b_ce2,
                                            float* __restrict__ cbias) {
    __shared__ __align__(16) float smem[8768];   // 35 KB, aliased per job
    int bid = blockIdx.x, t = threadIdx.x;

    if (bid < 64) {                         // ---- coverage-bias (no gate g)
        float* w1s = smem;                  // 256
        float* b1s = smem + 256;            // 256
        float* w2s = smem + 512;            // 256*16
        float* part = smem + 4608;          // 64 rows x 65 (padded, conflict-free)
        int b = bid >> 5, n0 = (bid & 31) * 64;
        // phase 0: weights -> LDS (coalesced, once per block)
        w1s[t] = w_ce1[t];
        b1s[t] = b_ce1[t];
        {
            float4* w2v = (float4*)w2s;
            const float4* g4 = (const float4*)w_ce2;
#pragma unroll
            for (int i = 0; i < 4; ++i) w2v[i * 256 + t] = g4[i * 256 + t];
        }
        __syncthreads();
        // phase 1: wave wv covers j in [wv*64, wv*64+64); lane = n_local.
        // all LDS reads are wave-uniform broadcasts; acc[16] in registers.
        int wv = t >> 6, lane2 = t & 63;
        float c = coverage[b * 2048 + n0 + lane2];
        float acc[16];
#pragma unroll
        for (int hh = 0; hh < 16; ++hh) acc[hh] = 0.f;
        for (int jj = 0; jj < 64; ++jj) {
            int j = wv * 64 + jj;
            float tv = fmaf(c, w1s[j], b1s[j]);
            tv = tv / (1.0f + __expf(-tv));   // silu
#pragma unroll
            for (int hh = 0; hh < 16; ++hh)
                acc[hh] = fmaf(tv, w2s[j * 16 + hh], acc[hh]);
        }
#pragma unroll
        for (int hh = 0; hh < 16; ++hh) part[lane2 * 65 + wv * 16 + hh] = acc[hh];
        __syncthreads();
        // phase 2: reduce 4 parts, write cbias
#pragma unroll
        for (int i = 0; i < 4; ++i) {
            int idx = t + i * 256;
            int nl = idx >> 4, hh = idx & 15;
            const float* pr = part + nl * 65 + hh;
            float s = pr[0] + pr[16] + pr[32] + pr[48];
            cbias[((size_t)b * 16 + hh) * 2048 + n0 + nl] = LOG2E * (s + b_ce2[hh]);
        }
    } else if (bid < 320) {                 // ---- pool partial sums
        int blk = bid - 64;
        int b = blk >> 7, ch = blk & 127;
        int c = t * 4;
        float s0 = 0.f, s1 = 0.f, s2 = 0.f, s3 = 0.f;
        for (int rr = 0; rr < 16; ++rr) {
            float4 v = *(const float4*)(x + (size_t)(b * Nc + ch * 16 + rr) * Dc + c);
            s0 += v.x; s1 += v.y; s2 += v.z; s3 += v.w;
        }
        atomicAdd(&pooled[b * Dc + c + 0], s0);
        atomicAdd(&pooled[b * Dc + c + 1], s1);
        atomicAdd(&pooled[b * Dc + c + 2], s2);
        atomicAdd(&pooled[b * Dc + c + 3], s3);
    } else if (bid < 1088) {                // ---- transpose w_qkv
        int bb = bid - 320;
        tr64_body(w_qkv, Wt, 1024, 3072, bb % 48, bb / 48, (bf16_t*)smem, t);
    } else if (bid < 1344) {                // ---- transpose w_out
        int bb = bid - 1088;
        tr64_body(w_out, WoT, 1024, 1024, bb & 15, bb >> 4, (bf16_t*)smem, t);
    } else {                                // ---- f2b: x -> bf16 (4 chunks/thread)
        int base = (bid - 1344) * 4096 + t * 4;
#pragma unroll
        for (int c = 0; c < 4; ++c) {
            int i = base + c * 1024;
            float4 v = *(const float4*)(x + i);
            bf16x4 o = { (bf16_t)v.x, (bf16_t)v.y, (bf16_t)v.z, (bf16_t)v.w };
            *(bf16x4*)(Xb + i) = o;
        }
    }
}

// ---------------------------------------------------------------------------
// QKV GEMM (y<24) + gate MLP (y==24, 32 blocks, 16 (b,j) pairs each).
// Q pre-scaled by C1 = 0.125*log2(e) so attn can use exp2 with no FMA.
__global__ __launch_bounds__(256) void qkv_gemm(const bf16_t* __restrict__ Xb,
                                                const bf16_t* __restrict__ Wt,
                                                bf16_t* __restrict__ Q,
                                                bf16_t* __restrict__ Kb,
                                                bf16_t* __restrict__ Vt,
                                                const float* __restrict__ pooled,
                                                const float* __restrict__ w_fg1,
                                                const float* __restrict__ b_fg1,
                                                const float* __restrict__ w_fg2,
                                                float* __restrict__ hacc) {
    __shared__ __align__(16) bf16_t At[128 * 32];
    __shared__ __align__(16) bf16_t Bt[128 * 32];
    int t = threadIdx.x;

    if (blockIdx.y == 24) {                 // gate MLP: hacc[b] += silu(h_j)*w_fg2[j]
        __shared__ float red[4];
        int blk = blockIdx.x;
        int b = blk >> 4, jb = (blk & 15) * 16;
        for (int jj = 0; jj < 16; ++jj) {
            int j = jb + jj;
            float p = 0.f;
#pragma unroll
            for (int i = 0; i < 4; ++i) {
                int d = t * 4 + i;
                p += pooled[b * 1024 + d] * w_fg1[d * 256 + j];
            }
#pragma unroll
            for (int off = 32; off > 0; off >>= 1) p += __shfl_down(p, off);
            if ((t & 63) == 0) red[t >> 6] = p;
            __syncthreads();
            if (t == 0) {
                float hj = (red[0] + red[1] + red[2] + red[3]) * (1.0f / 2048.0f) + b_fg1[j];
                hj = hj / (1.0f + __expf(-hj)); // silu
                atomicAdd(&hacc[b], hj * w_fg2[j]);
            }
            __syncthreads();
        }
        return;
    }

    int w = t >> 6, lane = t & 63;
    int l16 = lane & 15, quad = lane >> 4;
    int wm = w & 1, wx = w >> 1;
    int m0 = blockIdx.x * 128;
    int n0 = blockIdx.y * 128;
    f32x4 acc[4][4] = {};
    int sw = (l16 >> 2) & 3;

    for (int k0 = 0; k0 < 1024; k0 += 32) {
#pragma unroll
        for (int i = 0; i < 2; ++i) {
            int fb = i * 4096 + w * 1024;
            int f = fb + lane * 16;
            int row = f >> 6;
            int ch = (f >> 4) & 3;
            int sc = ch ^ ((row >> 2) & 3);
            glds16(Wt + (size_t)(n0 + row) * 1024 + k0 + sc * 8, At + (fb >> 1));
            glds16(Xb + (size_t)(m0 + row) * 1024 + k0 + sc * 8, Bt + (fb >> 1));
        }
        __syncthreads();
        bf16x8 afr[4], bfr[4];
#pragma unroll
        for (int mi = 0; mi < 4; ++mi)
            afr[mi] = *(const bf16x8*)(At + (wm * 64 + mi * 16 + l16) * 32 + ((quad ^ sw) * 8));
#pragma unroll
        for (int ni = 0; ni < 4; ++ni)
            bfr[ni] = *(const bf16x8*)(Bt + (wx * 64 + ni * 16 + l16) * 32 + ((quad ^ sw) * 8));
#pragma unroll
        for (int mi = 0; mi < 4; ++mi)
#pragma unroll
            for (int ni = 0; ni < 4; ++ni)
                acc[mi][ni] = MFMA16(afr[mi], bfr[ni], acc[mi][ni]);
        __syncthreads();
    }

    int sec = n0 >> 10;
    float scq = (sec == 0) ? C1 : 1.0f;
#pragma unroll
    for (int mi = 0; mi < 4; ++mi) {
        int gc = n0 + wm * 64 + mi * 16 + quad * 4;
        int dcol = gc & 1023;
        int h = dcol >> 6, hd = dcol & 63;
#pragma unroll
        for (int ni = 0; ni < 4; ++ni) {
            int gx = m0 + wx * 64 + ni * 16 + l16;
            int b = gx >> 11, n = gx & 2047;
            size_t bh = (size_t)(b * 16 + h);
            if (sec == 2) {
#pragma unroll
                for (int r = 0; r < 4; ++r)
                    Vt[(bh * 64 + hd + r) * 2048 + n] = (bf16_t)acc[mi][ni][r];
            } else {
                bf16x4 pk = { (bf16_t)(acc[mi][ni][0] * scq), (bf16_t)(acc[mi][ni][1] * scq),
                              (bf16_t)(acc[mi][ni][2] * scq), (bf16_t)(acc[mi][ni][3] * scq) };
                bf16_t* dst = (sec == 0 ? Q : Kb);
                *(bf16x4*)(dst + (bh * 2048 + n) * 64 + hd) = pk;
            }
        }
    }
}

// ---------------------------------------------------------------------------
// Flash attention v7: 4 waves x 32 q = 128 q/block, grid (16,32) — the proven
// round-2 shape — with counted-vmcnt pipeline, setprio, hoisted LDS offsets,
// and gate g applied to the staged bias.
__global__ __launch_bounds__(256) void attn_k(const bf16_t* __restrict__ Q,
                                              const bf16_t* __restrict__ Kb,
                                              const bf16_t* __restrict__ Vt,
                                              const float* __restrict__ cbias,
                                              const float* __restrict__ hacc,
                                              const float* __restrict__ b_fg2,
                                              bf16_t* __restrict__ O) {
    __shared__ __align__(16) bf16_t kbuf[2][64 * 64];
    __shared__ __align__(16) bf16_t vbuf[2][64 * 64];
    __shared__ __align__(16) float bbias[2][64];
    int t = threadIdx.x, w = t >> 6, lane = t & 63;
    int l16 = lane & 15, quad = lane >> 4;
    int bh = blockIdx.y;
    int b = bh >> 4, h = bh & 15;
    int qa = blockIdx.x * 128 + w * 32;
    const bf16_t* Qh = Q + (size_t)bh * 2048 * 64;
    const bf16_t* Kh = Kb + (size_t)bh * 2048 * 64;
    const bf16_t* Vh = Vt + (size_t)bh * 64 * 2048;
    const float* bih = cbias + (size_t)bh * 2048;
    float g = 1.0f / (1.0f + __expf(-(hacc[b] + b_fg2[0])));

    int fb0 = w * 2048, fb1 = fb0 + 1024;   // byte ranges staged by this wave
    int f0 = fb0 + lane * 16, f1 = fb1 + lane * 16;
    int krow0 = f0 >> 7, kch0 = ((f0 >> 4) & 7) ^ (krow0 & 7);
    int krow1 = f1 >> 7, kch1 = ((f1 >> 4) & 7) ^ (krow1 & 7);

    bf16x8 qf[2][2];
#pragma unroll
    for (int qt = 0; qt < 2; ++qt)
#pragma unroll
        for (int dh = 0; dh < 2; ++dh)
            qf[qt][dh] = *(const bf16x8*)(Qh + (size_t)(qa + qt * 16 + l16) * 64 + dh * 32 + quad * 8);

    f32x4 o[2][4] = {};
    f32x4 lacc[2] = {};
    bf16x8 onesb;
#pragma unroll
    for (int i = 0; i < 8; ++i) onesb[i] = (bf16_t)1.0f;
    int swl = l16 & 7;
    int qh = quad >> 1, ql = quad & 1;

    // hoisted per-thread LDS read offsets (elements); loop adds immediates only
    int bk0 = l16 * 64 + ((quad ^ swl) * 8);
    int bk1 = l16 * 64 + (((4 + quad) ^ swl) * 8);
    int bv0 = l16 * 64 + ql * 4 + ((qh ^ swl) * 8);
    int bv1 = l16 * 64 + ql * 4 + (((2 + qh) ^ swl) * 8);
    int bv2 = l16 * 64 + ql * 4 + (((4 + qh) ^ swl) * 8);
    int bv3 = l16 * 64 + ql * 4 + (((6 + qh) ^ swl) * 8);

    // stage tile into buffer bf: 5 vmem ops per wave (K2 + V2 + bias1)
    auto stage = [&](int tile_, int bf) {
        int jn = tile_ * 64;
        glds16(Kh + (size_t)(jn + krow0) * 64 + kch0 * 8, &kbuf[bf][fb0 >> 1]);
        glds16(Kh + (size_t)(jn + krow1) * 64 + kch1 * 8, &kbuf[bf][fb1 >> 1]);
        glds16(Vh + (size_t)krow0 * 2048 + jn + kch0 * 8, &vbuf[bf][fb0 >> 1]);
        glds16(Vh + (size_t)krow1 * 2048 + jn + kch1 * 8, &vbuf[bf][fb1 >> 1]);
        glds4(bih + jn + lane, &bbias[bf][0]);   // all waves write same values (benign)
    };

    stage(0, 0);

    for (int it = 0; it < 32; ++it) {
        int sel = it & 1;
        asm volatile("s_waitcnt lgkmcnt(0)" ::: "memory");
        __builtin_amdgcn_s_barrier();            // everyone done reading buf[sel^1]
        if (it + 1 < 32) {
            stage(it + 1, sel ^ 1);              // outstanding: 10
            asm volatile("s_waitcnt vmcnt(5)" ::: "memory");   // tile-it loads done
        } else {
            asm volatile("s_waitcnt vmcnt(0)" ::: "memory");
        }
        __builtin_amdgcn_s_barrier();            // tile-it data visible to all waves
        __builtin_amdgcn_sched_barrier(0);

        const bf16_t* kb = &kbuf[sel][0];
        const bf16_t* vb = &vbuf[sel][0];
        const float* bp = &bbias[sel][0];

        f32x4 s[2][4];
        __builtin_amdgcn_s_setprio(1);
#pragma unroll
        for (int kt = 0; kt < 4; ++kt) {
            f32x4 bv = *(const f32x4*)(bp + kt * 16 + quad * 4);   // LDS broadcast
            f32x4 bi = { bv[0] * g, bv[1] * g, bv[2] * g, bv[3] * g };
            bf16x8 kf0 = *(const bf16x8*)(kb + kt * 1024 + bk0);
            bf16x8 kf1 = *(const bf16x8*)(kb + kt * 1024 + bk1);
#pragma unroll
            for (int qt = 0; qt < 2; ++qt) {
                s[qt][kt] = MFMA16(kf0, qf[qt][0], bi);
                s[qt][kt] = MFMA16(kf1, qf[qt][1], s[qt][kt]);
            }
        }
        __builtin_amdgcn_s_setprio(0);

        bf16x8 pf[2][2];
#pragma unroll
        for (int qt = 0; qt < 2; ++qt) {
#pragma unroll
            for (int kt = 0; kt < 4; ++kt)
#pragma unroll
                for (int r = 0; r < 4; ++r)
                    s[qt][kt][r] = __builtin_amdgcn_exp2f(s[qt][kt][r]);
#pragma unroll
            for (int pv = 0; pv < 2; ++pv) {
                bf16x8 tmp;
#pragma unroll
                for (int i = 0; i < 4; ++i) {
                    tmp[i]     = (bf16_t)s[qt][2 * pv][i];
                    tmp[i + 4] = (bf16_t)s[qt][2 * pv + 1][i];
                }
                pf[qt][pv] = tmp;
            }
        }

        __builtin_amdgcn_s_setprio(1);
#pragma unroll
        for (int qt = 0; qt < 2; ++qt) {
            lacc[qt] = MFMA16(pf[qt][0], onesb, lacc[qt]);
            lacc[qt] = MFMA16(pf[qt][1], onesb, lacc[qt]);
        }
#pragma unroll
        for (int dt = 0; dt < 4; ++dt) {
            bf16x4 va0 = *(const bf16x4*)(vb + dt * 1024 + bv0);
            bf16x4 vc0 = *(const bf16x4*)(vb + dt * 1024 + bv1);
            bf16x8 vf0 = __builtin_shufflevector(va0, vc0, 0, 1, 2, 3, 4, 5, 6, 7);
            bf16x4 va1 = *(const bf16x4*)(vb + dt * 1024 + bv2);
            bf16x4 vc1 = *(const bf16x4*)(vb + dt * 1024 + bv3);
            bf16x8 vf1 = __builtin_shufflevector(va1, vc1, 0, 1, 2, 3, 4, 5, 6, 7);
#pragma unroll
            for (int qt = 0; qt < 2; ++qt) {
                o[qt][dt] = MFMA16(pf[qt][0], vf0, o[qt][dt]);
                o[qt][dt] = MFMA16(pf[qt][1], vf1, o[qt][dt]);
            }
        }
        __builtin_amdgcn_s_setprio(0);
    }

#pragma unroll
    for (int qt = 0; qt < 2; ++qt) {
        f32x4 rinv;
#pragma unroll
        for (int r = 0; r < 4; ++r) rinv[r] = 1.0f / lacc[qt][r];
#pragma unroll
        for (int dt = 0; dt < 4; ++dt)
#pragma unroll
            for (int r = 0; r < 4; ++r) {
                int row = qa + qt * 16 + quad * 4 + r;
                O[(size_t)(b * 2048 + row) * 1024 + h * 64 + dt * 16 + l16] =
                    (bf16_t)(o[qt][dt][r] * rinv[r]);
            }
    }
}

// ---------------------------------------------------------------------------
__global__ __launch_bounds__(256) void out_gemm(const bf16_t* __restrict__ A,
                                                const bf16_t* __restrict__ Wt,
                                                const float* __restrict__ bias,
                                                float* __restrict__ Cout) {
    __shared__ __align__(16) bf16_t At[128 * 32];
    __shared__ __align__(16) bf16_t Bt[128 * 32];
    int t = threadIdx.x, w = t >> 6, lane = t & 63;
    int l16 = lane & 15, quad = lane >> 4;
    int wm = w & 1, wx = w >> 1;
    int m0 = blockIdx.x * 128;
    int n0 = blockIdx.y * 128;
    f32x4 acc[4][4] = {};
    int sw = (l16 >> 2) & 3;

    for (int k0 = 0; k0 < 1024; k0 += 32) {
#pragma unroll
        for (int i = 0; i < 2; ++i) {
            int fb = i * 4096 + w * 1024;
            int f = fb + lane * 16;
            int row = f >> 6;
            int ch = (f >> 4) & 3;
            int sc = ch ^ ((row >> 2) & 3);
            glds16(Wt + (size_t)(n0 + row) * 1024 + k0 + sc * 8, At + (fb >> 1));
            glds16(A + (size_t)(m0 + row) * 1024 + k0 + sc * 8, Bt + (fb >> 1));
        }
        __syncthreads();
        bf16x8 afr[4], bfr[4];
#pragma unroll
        for (int mi = 0; mi < 4; ++mi)
            afr[mi] = *(const bf16x8*)(At + (wm * 64 + mi * 16 + l16) * 32 + ((quad ^ sw) * 8));
#pragma unroll
        for (int ni = 0; ni < 4; ++ni)
            bfr[ni] = *(const bf16x8*)(Bt + (wx * 64 + ni * 16 + l16) * 32 + ((quad ^ sw) * 8));
#pragma unroll
        for (int mi = 0; mi < 4; ++mi)
#pragma unroll
            for (int ni = 0; ni < 4; ++ni)
                acc[mi][ni] = MFMA16(afr[mi], bfr[ni], acc[mi][ni]);
        __syncthreads();
    }

#pragma unroll
    for (int mi = 0; mi < 4; ++mi) {
        int gc = n0 + wm * 64 + mi * 16 + quad * 4;
        float4 bv = *(const float4*)(bias + gc);
#pragma unroll
        for (int ni = 0; ni < 4; ++ni) {
            int gx = m0 + wx * 64 + ni * 16 + l16;
            float4 ov = { acc[mi][ni][0] + bv.x, acc[mi][ni][1] + bv.y,
                          acc[mi][ni][2] + bv.z, acc[mi][ni][3] + bv.w };
            *(float4*)(Cout + (size_t)gx * 1024 + gc) = ov;
        }
    }
}

// ---------------------------------------------------------------------------
extern "C" void kernel_launch(void* const* d_in, const int* in_sizes, int n_in,
                              void* d_out, int out_size, void* d_ws, size_t ws_size,
                              hipStream_t stream) {
    const float* x     = (const float*)d_in[0];
    const float* cov   = (const float*)d_in[1];
    const float* w_qkv = (const float*)d_in[2];
    const float* w_out = (const float*)d_in[3];
    const float* b_out = (const float*)d_in[4];
    const float* w_ce1 = (const float*)d_in[5];
    const float* b_ce1 = (const float*)d_in[6];
    const float* w_ce2 = (const float*)d_in[7];
    const float* b_ce2 = (const float*)d_in[8];
    const float* w_fg1 = (const float*)d_in[9];
    const float* b_fg1 = (const float*)d_in[10];
    const float* w_fg2 = (const float*)d_in[11];
    const float* b_fg2 = (const float*)d_in[12];

    char* ws = (char*)d_ws;
    bf16_t* Wt     = (bf16_t*)(ws);              // 3072x1024
    bf16_t* WoT    = (bf16_t*)(ws + 6291456);    // 1024x1024
    bf16_t* Xb     = (bf16_t*)(ws + 8388608);    // 4096x1024
    bf16_t* Qb     = (bf16_t*)(ws + 16777216);   // (2,16,2048,64)
    bf16_t* Kbb    = (bf16_t*)(ws + 25165824);   // (2,16,2048,64)
    bf16_t* Vt     = (bf16_t*)(ws + 33554432);   // (2,16,64,2048)
    bf16_t* Ob     = (bf16_t*)(ws + 41943040);   // (4096,1024)
    float*  pooled = (float*)(ws + 50331648);    // 2x1024 f32
    float*  hacc   = (float*)(ws + 50339840);    // 2 f32 (contiguous after pooled)
    float*  biasb  = (float*)(ws + 50340096);    // 2x16x2048 f32 (no g applied)

    // pooled (8192 B) and hacc (8 B) are contiguous: one memset
    hipMemsetAsync(pooled, 0, 8200, stream);
    prep<<<2368, 256, 0, stream>>>(x, Xb, w_qkv, Wt, w_out, WoT, pooled,
                                   cov, w_ce1, b_ce1, w_ce2, b_ce2, biasb);
    qkv_gemm<<<dim3(32, 25), 256, 0, stream>>>(Xb, Wt, Qb, Kbb, Vt,
                                               pooled, w_fg1, b_fg1, w_fg2, hacc);
    attn_k<<<dim3(16, 32), 256, 0, stream>>>(Qb, Kbb, Vt, biasb, hacc, b_fg2, Ob);
    out_gemm<<<dim3(32, 8), 256, 0, stream>>>(Ob, WoT, b_out, (float*)d_out);
}